// Round 7
// baseline (249.406 us; speedup 1.0000x reference)
//
#include <hip/hip_runtime.h>
#include <hip/hip_bf16.h>
#include <stdint.h>

// TripletLoss (n=4096, d=2048, K=4) — fused bf16-MFMA distance + mining.
//   1. prep: fp32 -> bf16 matrix (ws) + row sum-of-squares sq[] + neg_min init
//      + completion-counter zero
//   2. gemm: upper-tri 256x256 tiles of A@A^T, R4-proven 8-phase schedule
//      (2 barriers/phase, counted vmcnt(4) after MFMA at ph4/ph8), 512 thr
//      (2Mx4N waves, 128x64/wave), 16x16x32 MFMA, BK=64, 128 KiB dbuf LDS,
//      XOR-swizzled staging (0 bank conflicts), triangular grid (136=8x17).
//      NEW: fragment double-buffering (afE/afO, bfrA..D) -> every register
//      WAR gap >= 3 phases (was adjacent-phase), letting ds_read writeback
//      proceed while prior MFMAs drain.
//      Fused epilogue: dist = sqrt(max(sq_i+sq_j-2*dot,1e-12)); row+col mins
//      -> atomicMin; diagonal tiles emit within-identity dist_ap.
//      LAST block (device counter) computes loss/prec in-kernel.

#define N_ROWS 4096
#define DIM    2048
#define P_IDS  1024
#define NPAIR  (P_IDS * 6)
#define MARGIN 0.3f
#define BK     64
#define NT     (DIM / BK)   // 32 K-tiles
#define NIT    (NT / 2)     // 16 iterations (2 K-tiles each)
#define NTILE2 16           // 4096 / 256
#define NBLK2  136          // NTILE2*(NTILE2+1)/2 = 8*17

typedef unsigned short u16;
typedef __attribute__((ext_vector_type(8))) short bf16x8;
typedef __attribute__((ext_vector_type(4))) float f32x4;

__device__ __forceinline__ u16 f2bf(float f) {
    unsigned u = __float_as_uint(f);
    unsigned r = (u + 0x7fffu + ((u >> 16) & 1u)) >> 16;  // RTNE
    return (u16)r;
}

__global__ __launch_bounds__(256) void prep_kernel(const float* __restrict__ in,
                                                   u16* __restrict__ bfm,
                                                   float* __restrict__ sq,
                                                   unsigned* __restrict__ neg_bits,
                                                   unsigned* __restrict__ done_ctr) {
    const int row = blockIdx.x;
    const int t = threadIdx.x;
    const float4* rp = (const float4*)(in + (size_t)row * DIM);
    float4 v0 = rp[t * 2 + 0];
    float4 v1 = rp[t * 2 + 1];
    float s = v0.x * v0.x + v0.y * v0.y + v0.z * v0.z + v0.w * v0.w
            + v1.x * v1.x + v1.y * v1.y + v1.z * v1.z + v1.w * v1.w;
    uint4 o;
    o.x = (unsigned)f2bf(v0.x) | ((unsigned)f2bf(v0.y) << 16);
    o.y = (unsigned)f2bf(v0.z) | ((unsigned)f2bf(v0.w) << 16);
    o.z = (unsigned)f2bf(v1.x) | ((unsigned)f2bf(v1.y) << 16);
    o.w = (unsigned)f2bf(v1.z) | ((unsigned)f2bf(v1.w) << 16);
    ((uint4*)(bfm + (size_t)row * DIM))[t] = o;
    #pragma unroll
    for (int m = 32; m; m >>= 1) s += __shfl_down(s, m, 64);
    __shared__ float red[4];
    if ((t & 63) == 0) red[t >> 6] = s;
    __syncthreads();
    if (t == 0) {
        sq[row] = red[0] + red[1] + red[2] + red[3];
        neg_bits[row] = 0x7F800000u;  // +inf
        if (row == 0) done_ctr[0] = 0;
    }
}

__global__ __launch_bounds__(512, 2) void gemm_kernel(const u16* __restrict__ bfm,
                                                      const float* __restrict__ sq,
                                                      unsigned* __restrict__ neg_bits,
                                                      float* __restrict__ dist_ap,
                                                      unsigned* __restrict__ done_ctr,
                                                      float* __restrict__ out) {
    extern __shared__ char smem[];          // 128 KiB dynamic LDS
    u16* const Asb = (u16*)smem;            // [2][256][64] u16 (64 KiB)
    u16* const Bsb = (u16*)(smem + 65536);  // [2][256][64] u16 (64 KiB)
    #define AS(B,R,C) Asb[((B) << 14) + ((R) << 6) + (C)]
    #define BS(B,R,C) Bsb[((B) << 14) + ((R) << 6) + (C)]

    // Bijective XCD-chunk swizzle (136 = 8 * 17).
    const int bid = (blockIdx.x & 7) * (NBLK2 / 8) + (blockIdx.x >> 3);
    int rem = bid, bi = 0;
    while (rem >= NTILE2 - bi) { rem -= NTILE2 - bi; ++bi; }
    const int bj = bi + rem;   // bi <= bj

    const int t = threadIdx.x;
    const int lane = t & 63;
    const int wave = t >> 6;             // 0..7
    const int wr = (wave >> 2) * 128;    // M-half (2 waves)
    const int wc = (wave & 3) * 64;      // N-quarter (4 waves)
    const int lr = lane & 15;
    const int lk = (lane >> 4) * 8;
    f32x4 acc[8][4] = {};

    const int rowA0 = bi * 256;
    const int rowB0 = bj * 256;
    // XOR-swizzled staging: pre-swizzle global col so linear LDS write lands
    // at byte r*128 + ((g ^ (r&7))*16); read applies the same XOR.
    const int sr  = lane >> 3;
    const int scz = ((lane & 7) ^ sr) * 8;
    const u16* gA = bfm + (size_t)(rowA0 + sr) * DIM + scz;
    const u16* gB = bfm + (size_t)(rowB0 + sr) * DIM + scz;

    // Stage one 128-row half-tile (16 KiB) of A or B: 2 gloads/wave.
    #define STAGE_HT(GBASE, LDSB, BUF, H, KT)                                     \
        { _Pragma("unroll")                                                       \
          for (int g = 0; g < 2; ++g) {                                           \
              const int chunk = (H) * 16 + wave * 2 + g;                          \
              __builtin_amdgcn_global_load_lds(                                   \
                  (const __attribute__((address_space(1))) void*)                 \
                      ((GBASE) + (size_t)chunk * 8 * DIM + (KT) * 64),            \
                  (__attribute__((address_space(3))) void*)                       \
                      ((char*)(LDSB) + (BUF) * 32768 + chunk * 1024),             \
                  16, 0, 0);                                                      \
          } }
    #define STAGE_A(BUF, H, KT) STAGE_HT(gA, Asb, BUF, H, KT)
    #define STAGE_B(BUF, H, KT) STAGE_HT(gB, Bsb, BUF, H, KT)

    // Fragment buffers: afE/afO alternate per A-load; bfrA..D rotate per
    // B-load. Every ds_read targets registers whose last MFMA reader is
    // >= 3 phases back (no adjacent-phase WAR skid).
    bf16x8 afE[8], afO[8], bfrA[4], bfrB[4], bfrC[4], bfrD[4];
    #define LOAD_AF(DST, BUF, MH)                                                 \
        { _Pragma("unroll") for (int m = 0; m < 4; ++m)                           \
          _Pragma("unroll") for (int ks = 0; ks < 2; ++ks)                        \
              DST[m * 2 + ks] = *(const bf16x8*)&AS(BUF,                          \
                  wr + ((MH) * 4 + m) * 16 + lr,                                  \
                  (ks * 32 + lk) ^ ((lr & 7) * 8)); }
    #define LOAD_BF(DST, BUF, NH)                                                 \
        { _Pragma("unroll") for (int n = 0; n < 2; ++n)                           \
          _Pragma("unroll") for (int ks = 0; ks < 2; ++ks)                        \
              DST[n * 2 + ks] = *(const bf16x8*)&BS(BUF,                          \
                  wc + ((NH) * 2 + n) * 16 + lr,                                  \
                  (ks * 32 + lk) ^ ((lr & 7) * 8)); }

    #define MFMA_Q(MH, NH, AF, BF)                                                \
        { __builtin_amdgcn_s_setprio(1);                                          \
          _Pragma("unroll") for (int m = 0; m < 4; ++m)                           \
          _Pragma("unroll") for (int n = 0; n < 2; ++n)                           \
          _Pragma("unroll") for (int ks = 0; ks < 2; ++ks)                        \
              acc[(MH) * 4 + m][(NH) * 2 + n] =                                   \
                  __builtin_amdgcn_mfma_f32_16x16x32_bf16(                        \
                      AF[m * 2 + ks], BF[n * 2 + ks],                             \
                      acc[(MH) * 4 + m][(NH) * 2 + n], 0, 0, 0);                  \
          __builtin_amdgcn_s_setprio(0); }

    #define BARR() __builtin_amdgcn_s_barrier()
    #define VMW(N) asm volatile("s_waitcnt vmcnt(" #N ")" ::: "memory")

    // Prologue: A(0), B(0) -> buf0; B(1) -> buf1. (A(1) staged in iter0 ph1-2.)
    STAGE_A(0, 0, 0); STAGE_A(0, 1, 0);
    STAGE_B(0, 0, 0); STAGE_B(0, 1, 0);
    STAGE_B(1, 0, 1); STAGE_B(1, 1, 1);
    VMW(0);
    BARR();

    for (int i = 0; i < NIT - 1; ++i) {
        const int t2 = 2 * i;
        // ph1: compute t2 (buf0) quadrant (0,0); stage A(t2+1).h0 -> buf1
        LOAD_AF(afE, 0, 0); LOAD_BF(bfrA, 0, 0);
        STAGE_A(1, 0, t2 + 1);
        BARR(); MFMA_Q(0, 0, afE, bfrA); BARR();
        // ph2
        LOAD_BF(bfrB, 0, 1);
        STAGE_A(1, 1, t2 + 1);
        BARR(); MFMA_Q(0, 1, afE, bfrB); BARR();
        // ph3
        LOAD_AF(afO, 0, 1);
        STAGE_B(0, 0, t2 + 2);
        BARR(); MFMA_Q(1, 1, afO, bfrB); BARR();
        // ph4: counted drain after MFMA (A(t+1) landed for ph5-8)
        STAGE_B(0, 1, t2 + 2);
        BARR(); MFMA_Q(1, 0, afO, bfrA); VMW(4); BARR();
        // ph5: compute t2+1 (buf1); stage A(t2+2).h0 -> buf0
        LOAD_AF(afE, 1, 0); LOAD_BF(bfrC, 1, 0);
        STAGE_A(0, 0, t2 + 2);
        BARR(); MFMA_Q(0, 0, afE, bfrC); BARR();
        // ph6
        LOAD_BF(bfrD, 1, 1);
        STAGE_A(0, 1, t2 + 2);
        BARR(); MFMA_Q(0, 1, afE, bfrD); BARR();
        // ph7
        LOAD_AF(afO, 1, 1);
        STAGE_B(1, 0, t2 + 3);
        BARR(); MFMA_Q(1, 1, afO, bfrD); BARR();
        // ph8: counted drain (A(t+2)+B(t+2) landed for next iter ph1-4)
        STAGE_B(1, 1, t2 + 3);
        BARR(); MFMA_Q(1, 0, afO, bfrC); VMW(4); BARR();
    }
    // Peeled last iteration (t2 = 30): no stages for tiles 32/33.
    {
        LOAD_AF(afE, 0, 0); LOAD_BF(bfrA, 0, 0);
        STAGE_A(1, 0, NT - 1);
        BARR(); MFMA_Q(0, 0, afE, bfrA); BARR();
        LOAD_BF(bfrB, 0, 1);
        STAGE_A(1, 1, NT - 1);
        BARR(); MFMA_Q(0, 1, afE, bfrB); BARR();
        LOAD_AF(afO, 0, 1);
        BARR(); MFMA_Q(1, 1, afO, bfrB); BARR();
        BARR(); MFMA_Q(1, 0, afO, bfrA); VMW(0); BARR();
        LOAD_AF(afE, 1, 0); LOAD_BF(bfrC, 1, 0);
        BARR(); MFMA_Q(0, 0, afE, bfrC); BARR();
        LOAD_BF(bfrD, 1, 1);
        BARR(); MFMA_Q(0, 1, afE, bfrD); BARR();
        LOAD_AF(afO, 1, 1);
        BARR(); MFMA_Q(1, 1, afO, bfrD); BARR();
        MFMA_Q(1, 0, afO, bfrC);
    }

    // ---- fused epilogue ----
    const bool diag = (bi == bj);
    const int l4 = lane >> 4, l15 = lane & 15;
    float sqc[4];
    #pragma unroll
    for (int n = 0; n < 4; ++n) sqc[n] = sq[rowB0 + wc + n * 16 + l15];
    float colmin[4] = {INFINITY, INFINITY, INFINITY, INFINITY};

    #pragma unroll
    for (int m = 0; m < 8; ++m) {
        #pragma unroll
        for (int r = 0; r < 4; ++r) {
            const int grow = rowA0 + wr + m * 16 + l4 * 4 + r;
            const float sqr = sq[grow];
            float rmin = INFINITY;
            #pragma unroll
            for (int n = 0; n < 4; ++n) {
                const int gcol = rowB0 + wc + n * 16 + l15;
                const float d2 = sqr + sqc[n] - 2.0f * acc[m][n][r];
                const float d = sqrtf(fmaxf(d2, 1e-12f));
                float cand = d;
                if (diag && ((grow >> 2) == (gcol >> 2))) {
                    if (grow < gcol) {  // within-identity pair (a<b)
                        const int p = grow >> 2;
                        const int a = grow & 3, b = gcol & 3;
                        dist_ap[p * 6 + (a * (7 - a)) / 2 + (b - a - 1)] = d;
                    }
                    cand = INFINITY;  // mask positives from mining
                }
                rmin = fminf(rmin, cand);
                colmin[n] = fminf(colmin[n], cand);
            }
            rmin = fminf(rmin, __shfl_xor(rmin, 1, 64));
            rmin = fminf(rmin, __shfl_xor(rmin, 2, 64));
            rmin = fminf(rmin, __shfl_xor(rmin, 4, 64));
            rmin = fminf(rmin, __shfl_xor(rmin, 8, 64));
            if (l15 == 0) atomicMin(&neg_bits[grow], __float_as_uint(rmin));
        }
    }
    if (!diag) {  // transpose contribution (col mins)
        #pragma unroll
        for (int n = 0; n < 4; ++n) {
            float v = colmin[n];
            v = fminf(v, __shfl_xor(v, 16, 64));
            v = fminf(v, __shfl_xor(v, 32, 64));
            if (l4 == 0)
                atomicMin(&neg_bits[rowB0 + wc + n * 16 + l15], __float_as_uint(v));
        }
    }

    // ---- fused finalize: last block to finish computes loss/prec ----
    __threadfence();  // release dist_ap stores + atomicMins
    __shared__ unsigned lastflag;
    if (t == 0) lastflag = (atomicAdd(done_ctr, 1u) == NBLK2 - 1) ? 1u : 0u;
    __syncthreads();
    if (lastflag) {
        __threadfence();  // acquire other blocks' writes
        float sum = 0.f, cnt = 0.f;
        for (int e = t; e < NPAIR; e += 512) {
            const int p = e / 6;
            const int idx = e - p * 6;
            const int a = (idx < 3) ? 0 : ((idx < 5) ? 1 : 2);  // triu jj, K=4
            const float an = __uint_as_float(neg_bits[p * 4 + a]);
            const float ap = dist_ap[e];
            sum += fmaxf(ap - an + MARGIN, 0.f);
            cnt += (an > ap) ? 1.f : 0.f;
        }
        #pragma unroll
        for (int m2 = 32; m2; m2 >>= 1) {
            sum += __shfl_down(sum, m2, 64);
            cnt += __shfl_down(cnt, m2, 64);
        }
        float* red = (float*)smem;  // LDS free after K-loop
        if (lane == 0) { red[wave] = sum; red[8 + wave] = cnt; }
        __syncthreads();
        if (t == 0) {
            float s = 0.f, c = 0.f;
            #pragma unroll
            for (int w = 0; w < 8; ++w) { s += red[w]; c += red[8 + w]; }
            out[0] = s / (float)NPAIR;
            out[1] = c / (float)NPAIR;
        }
    }
}

extern "C" void kernel_launch(void* const* d_in, const int* in_sizes, int n_in,
                              void* d_out, int out_size, void* d_ws, size_t ws_size,
                              hipStream_t stream) {
    const float* inputs = (const float*)d_in[0];
    float* out = (float*)d_out;
    char* ws = (char*)d_ws;
    u16* bfm = (u16*)ws;                                       // 16 MiB
    float* sq = (float*)(ws + (size_t)N_ROWS * DIM * 2);       // 16 KiB
    unsigned* neg_bits = (unsigned*)((char*)sq + N_ROWS * 4);  // 16 KiB
    float* dist_ap = (float*)((char*)neg_bits + N_ROWS * 4);   // 24 KiB
    unsigned* done_ctr = (unsigned*)((char*)dist_ap + NPAIR * 4);

    prep_kernel<<<N_ROWS, 256, 0, stream>>>(inputs, bfm, sq, neg_bits, done_ctr);
    gemm_kernel<<<NBLK2, 512, 131072, stream>>>(bfm, sq, neg_bits, dist_ap,
                                                done_ctr, out);
}

// Round 8
// 92.058 us; speedup vs baseline: 2.7092x; 2.7092x over previous
//
#include <hip/hip_runtime.h>
#include <hip/hip_bf16.h>
#include <stdint.h>

// TripletLoss (n=4096, d=2048, K=4) — fused bf16-MFMA distance + mining.
//   1. prep: fp32 -> bf16 matrix (ws) + row sum-of-squares sq[] + neg_min init
//   2. gemm: upper-tri 256x256 tiles of A@A^T, 8-phase schedule, 512 thr
//      (2Mx4N waves, 128x64 per wave), MFMA 16x16x32, BK=64, 128 KiB dbuf
//      LDS, XOR-swizzled staging (0 bank conflicts), counted vmcnt(4) at
//      phases 4/8, s_setprio around MFMA clusters, triangular grid
//      (136 = 8 XCD x 17). Register budget note: acc 128 (AGPR) + frags 64
//      + addressing ~50 fits the 256/wave cap from __launch_bounds__(512,2);
//      do NOT add fragment buffers (R7: +128 VGPR -> scratch spill, 3x slow).
//      Fused epilogue: dist = sqrt(max(sq_i+sq_j-2*dot,1e-12)); row+col mins
//      -> atomicMin; diagonal tiles emit within-identity dist_ap.
//   3. finalize: loss = mean(relu(ap - an + margin)), prec = mean(an > ap)

#define N_ROWS 4096
#define DIM    2048
#define P_IDS  1024
#define NPAIR  (P_IDS * 6)
#define MARGIN 0.3f
#define BK     64
#define NT     (DIM / BK)   // 32 K-tiles
#define NIT    (NT / 2)     // 16 iterations (2 K-tiles each)
#define NTILE2 16           // 4096 / 256
#define NBLK2  136          // NTILE2*(NTILE2+1)/2 = 8*17

typedef unsigned short u16;
typedef __attribute__((ext_vector_type(8))) short bf16x8;
typedef __attribute__((ext_vector_type(4))) float f32x4;

__device__ __forceinline__ u16 f2bf(float f) {
    unsigned u = __float_as_uint(f);
    unsigned r = (u + 0x7fffu + ((u >> 16) & 1u)) >> 16;  // RTNE
    return (u16)r;
}

__global__ __launch_bounds__(256) void prep_kernel(const float* __restrict__ in,
                                                   u16* __restrict__ bfm,
                                                   float* __restrict__ sq,
                                                   unsigned* __restrict__ neg_bits) {
    const int row = blockIdx.x;
    const int t = threadIdx.x;
    const float4* rp = (const float4*)(in + (size_t)row * DIM);
    float4 v0 = rp[t * 2 + 0];
    float4 v1 = rp[t * 2 + 1];
    float s = v0.x * v0.x + v0.y * v0.y + v0.z * v0.z + v0.w * v0.w
            + v1.x * v1.x + v1.y * v1.y + v1.z * v1.z + v1.w * v1.w;
    uint4 o;
    o.x = (unsigned)f2bf(v0.x) | ((unsigned)f2bf(v0.y) << 16);
    o.y = (unsigned)f2bf(v0.z) | ((unsigned)f2bf(v0.w) << 16);
    o.z = (unsigned)f2bf(v1.x) | ((unsigned)f2bf(v1.y) << 16);
    o.w = (unsigned)f2bf(v1.z) | ((unsigned)f2bf(v1.w) << 16);
    ((uint4*)(bfm + (size_t)row * DIM))[t] = o;
    #pragma unroll
    for (int m = 32; m; m >>= 1) s += __shfl_down(s, m, 64);
    __shared__ float red[4];
    if ((t & 63) == 0) red[t >> 6] = s;
    __syncthreads();
    if (t == 0) {
        sq[row] = red[0] + red[1] + red[2] + red[3];
        neg_bits[row] = 0x7F800000u;  // +inf
    }
}

__global__ __launch_bounds__(512, 2) void gemm_kernel(const u16* __restrict__ bfm,
                                                      const float* __restrict__ sq,
                                                      unsigned* __restrict__ neg_bits,
                                                      float* __restrict__ dist_ap) {
    extern __shared__ char smem[];          // 128 KiB dynamic LDS
    u16* const Asb = (u16*)smem;            // [2][256][64] u16 (64 KiB)
    u16* const Bsb = (u16*)(smem + 65536);  // [2][256][64] u16 (64 KiB)
    #define AS(B,R,C) Asb[((B) << 14) + ((R) << 6) + (C)]
    #define BS(B,R,C) Bsb[((B) << 14) + ((R) << 6) + (C)]

    // Bijective XCD-chunk swizzle (136 = 8 * 17).
    const int bid = (blockIdx.x & 7) * (NBLK2 / 8) + (blockIdx.x >> 3);
    int rem = bid, bi = 0;
    while (rem >= NTILE2 - bi) { rem -= NTILE2 - bi; ++bi; }
    const int bj = bi + rem;   // bi <= bj

    const int t = threadIdx.x;
    const int lane = t & 63;
    const int wave = t >> 6;             // 0..7
    const int wr = (wave >> 2) * 128;    // M-half (2 waves)
    const int wc = (wave & 3) * 64;      // N-quarter (4 waves)
    const int lr = lane & 15;
    const int lk = (lane >> 4) * 8;
    f32x4 acc[8][4] = {};

    const int rowA0 = bi * 256;
    const int rowB0 = bj * 256;
    // XOR-swizzled staging: pre-swizzle global col so linear LDS write lands
    // at byte r*128 + ((g ^ (r&7))*16); read applies the same XOR.
    const int sr  = lane >> 3;
    const int scz = ((lane & 7) ^ sr) * 8;
    const u16* gA = bfm + (size_t)(rowA0 + sr) * DIM + scz;
    const u16* gB = bfm + (size_t)(rowB0 + sr) * DIM + scz;

    // Stage one 128-row half-tile (16 KiB) of A or B: 2 gloads/wave.
    #define STAGE_HT(GBASE, LDSB, BUF, H, KT)                                     \
        { _Pragma("unroll")                                                       \
          for (int g = 0; g < 2; ++g) {                                           \
              const int chunk = (H) * 16 + wave * 2 + g;                          \
              __builtin_amdgcn_global_load_lds(                                   \
                  (const __attribute__((address_space(1))) void*)                 \
                      ((GBASE) + (size_t)chunk * 8 * DIM + (KT) * 64),            \
                  (__attribute__((address_space(3))) void*)                       \
                      ((char*)(LDSB) + (BUF) * 32768 + chunk * 1024),             \
                  16, 0, 0);                                                      \
          } }
    #define STAGE_A(BUF, H, KT) STAGE_HT(gA, Asb, BUF, H, KT)
    #define STAGE_B(BUF, H, KT) STAGE_HT(gB, Bsb, BUF, H, KT)

    bf16x8 af[8], bfr0[4], bfr1[4];
    #define LOAD_AF(BUF, MH)                                                      \
        { _Pragma("unroll") for (int m = 0; m < 4; ++m)                           \
          _Pragma("unroll") for (int ks = 0; ks < 2; ++ks)                        \
              af[m * 2 + ks] = *(const bf16x8*)&AS(BUF,                           \
                  wr + ((MH) * 4 + m) * 16 + lr,                                  \
                  (ks * 32 + lk) ^ ((lr & 7) * 8)); }
    #define LOAD_BF(DST, BUF, NH)                                                 \
        { _Pragma("unroll") for (int n = 0; n < 2; ++n)                           \
          _Pragma("unroll") for (int ks = 0; ks < 2; ++ks)                        \
              DST[n * 2 + ks] = *(const bf16x8*)&BS(BUF,                          \
                  wc + ((NH) * 2 + n) * 16 + lr,                                  \
                  (ks * 32 + lk) ^ ((lr & 7) * 8)); }

    #define MFMA_Q(MH, NH, BF)                                                    \
        { __builtin_amdgcn_s_setprio(1);                                          \
          _Pragma("unroll") for (int m = 0; m < 4; ++m)                           \
          _Pragma("unroll") for (int n = 0; n < 2; ++n)                           \
          _Pragma("unroll") for (int ks = 0; ks < 2; ++ks)                        \
              acc[(MH) * 4 + m][(NH) * 2 + n] =                                   \
                  __builtin_amdgcn_mfma_f32_16x16x32_bf16(                        \
                      af[m * 2 + ks], BF[n * 2 + ks],                             \
                      acc[(MH) * 4 + m][(NH) * 2 + n], 0, 0, 0);                  \
          __builtin_amdgcn_s_setprio(0); }

    #define BARR() __builtin_amdgcn_s_barrier()
    #define VMW(N) asm volatile("s_waitcnt vmcnt(" #N ")" ::: "memory")

    // Prologue: A(0), B(0) -> buf0; B(1) -> buf1. (A(1) staged in iter0 ph1-2.)
    STAGE_A(0, 0, 0); STAGE_A(0, 1, 0);
    STAGE_B(0, 0, 0); STAGE_B(0, 1, 0);
    STAGE_B(1, 0, 1); STAGE_B(1, 1, 1);
    VMW(0);
    BARR();

    for (int i = 0; i < NIT - 1; ++i) {
        const int t2 = 2 * i;
        // ph1: compute t2 (buf0) quadrant (0,0); stage A(t2+1).h0 -> buf1
        LOAD_AF(0, 0); LOAD_BF(bfr0, 0, 0);
        STAGE_A(1, 0, t2 + 1);
        BARR(); MFMA_Q(0, 0, bfr0); BARR();
        // ph2
        LOAD_BF(bfr1, 0, 1);
        STAGE_A(1, 1, t2 + 1);
        BARR(); MFMA_Q(0, 1, bfr1); BARR();
        // ph3
        LOAD_AF(0, 1);
        STAGE_B(0, 0, t2 + 2);
        BARR(); MFMA_Q(1, 1, bfr1); BARR();
        // ph4: counted drain (A(t+1) landed; B(t+2) stays in flight)
        STAGE_B(0, 1, t2 + 2);
        BARR(); MFMA_Q(1, 0, bfr0); VMW(4); BARR();
        // ph5: compute t2+1 (buf1); stage A(t2+2).h0 -> buf0
        LOAD_AF(1, 0); LOAD_BF(bfr0, 1, 0);
        STAGE_A(0, 0, t2 + 2);
        BARR(); MFMA_Q(0, 0, bfr0); BARR();
        // ph6
        LOAD_BF(bfr1, 1, 1);
        STAGE_A(0, 1, t2 + 2);
        BARR(); MFMA_Q(0, 1, bfr1); BARR();
        // ph7
        LOAD_AF(1, 1);
        STAGE_B(1, 0, t2 + 3);
        BARR(); MFMA_Q(1, 1, bfr1); BARR();
        // ph8: counted drain (B(t+2), A(t+2) landed; B(t+3) in flight)
        STAGE_B(1, 1, t2 + 3);
        BARR(); MFMA_Q(1, 0, bfr0); VMW(4); BARR();
    }
    // Peeled last iteration (t2 = 30): no stages for tiles 32/33.
    {
        LOAD_AF(0, 0); LOAD_BF(bfr0, 0, 0);
        STAGE_A(1, 0, NT - 1);
        BARR(); MFMA_Q(0, 0, bfr0); BARR();
        LOAD_BF(bfr1, 0, 1);
        STAGE_A(1, 1, NT - 1);
        BARR(); MFMA_Q(0, 1, bfr1); BARR();
        LOAD_AF(0, 1);
        BARR(); MFMA_Q(1, 1, bfr1); BARR();
        BARR(); MFMA_Q(1, 0, bfr0); VMW(0); BARR();
        LOAD_AF(1, 0); LOAD_BF(bfr0, 1, 0);
        BARR(); MFMA_Q(0, 0, bfr0); BARR();
        LOAD_BF(bfr1, 1, 1);
        BARR(); MFMA_Q(0, 1, bfr1); BARR();
        LOAD_AF(1, 1);
        BARR(); MFMA_Q(1, 1, bfr1); BARR();
        MFMA_Q(1, 0, bfr0);
    }

    // ---- fused epilogue ----
    const bool diag = (bi == bj);
    const int l4 = lane >> 4, l15 = lane & 15;
    float sqc[4];
    #pragma unroll
    for (int n = 0; n < 4; ++n) sqc[n] = sq[rowB0 + wc + n * 16 + l15];
    float colmin[4] = {INFINITY, INFINITY, INFINITY, INFINITY};

    #pragma unroll
    for (int m = 0; m < 8; ++m) {
        #pragma unroll
        for (int r = 0; r < 4; ++r) {
            const int grow = rowA0 + wr + m * 16 + l4 * 4 + r;
            const float sqr = sq[grow];
            float rmin = INFINITY;
            #pragma unroll
            for (int n = 0; n < 4; ++n) {
                const int gcol = rowB0 + wc + n * 16 + l15;
                const float d2 = sqr + sqc[n] - 2.0f * acc[m][n][r];
                const float d = sqrtf(fmaxf(d2, 1e-12f));
                float cand = d;
                if (diag && ((grow >> 2) == (gcol >> 2))) {
                    if (grow < gcol) {  // within-identity pair (a<b)
                        const int p = grow >> 2;
                        const int a = grow & 3, b = gcol & 3;
                        dist_ap[p * 6 + (a * (7 - a)) / 2 + (b - a - 1)] = d;
                    }
                    cand = INFINITY;  // mask positives from mining
                }
                rmin = fminf(rmin, cand);
                colmin[n] = fminf(colmin[n], cand);
            }
            rmin = fminf(rmin, __shfl_xor(rmin, 1, 64));
            rmin = fminf(rmin, __shfl_xor(rmin, 2, 64));
            rmin = fminf(rmin, __shfl_xor(rmin, 4, 64));
            rmin = fminf(rmin, __shfl_xor(rmin, 8, 64));
            if (l15 == 0) atomicMin(&neg_bits[grow], __float_as_uint(rmin));
        }
    }
    if (!diag) {  // transpose contribution (col mins)
        #pragma unroll
        for (int n = 0; n < 4; ++n) {
            float v = colmin[n];
            v = fminf(v, __shfl_xor(v, 16, 64));
            v = fminf(v, __shfl_xor(v, 32, 64));
            if (l4 == 0)
                atomicMin(&neg_bits[rowB0 + wc + n * 16 + l15], __float_as_uint(v));
        }
    }
}

__global__ __launch_bounds__(256) void finalize_kernel(const unsigned* __restrict__ neg_bits,
                                                       const float* __restrict__ dist_ap,
                                                       float* __restrict__ out) {
    const int t = threadIdx.x;
    float sum = 0.f, cnt = 0.f;
    for (int e = t; e < NPAIR; e += 256) {
        const int p = e / 6;
        const int idx = e - p * 6;
        const int a = (idx < 3) ? 0 : ((idx < 5) ? 1 : 2);  // triu jj for K=4
        const float an = __uint_as_float(neg_bits[p * 4 + a]);
        const float ap = dist_ap[e];
        sum += fmaxf(ap - an + MARGIN, 0.f);
        cnt += (an > ap) ? 1.f : 0.f;
    }
    #pragma unroll
    for (int m = 32; m; m >>= 1) {
        sum += __shfl_down(sum, m, 64);
        cnt += __shfl_down(cnt, m, 64);
    }
    __shared__ float rs[4], rc[4];
    if ((t & 63) == 0) { rs[t >> 6] = sum; rc[t >> 6] = cnt; }
    __syncthreads();
    if (t == 0) {
        out[0] = (rs[0] + rs[1] + rs[2] + rs[3]) / (float)NPAIR;
        out[1] = (rc[0] + rc[1] + rc[2] + rc[3]) / (float)NPAIR;
    }
}

extern "C" void kernel_launch(void* const* d_in, const int* in_sizes, int n_in,
                              void* d_out, int out_size, void* d_ws, size_t ws_size,
                              hipStream_t stream) {
    const float* inputs = (const float*)d_in[0];
    float* out = (float*)d_out;
    char* ws = (char*)d_ws;
    u16* bfm = (u16*)ws;                                       // 16 MiB
    float* sq = (float*)(ws + (size_t)N_ROWS * DIM * 2);       // 16 KiB
    unsigned* neg_bits = (unsigned*)((char*)sq + N_ROWS * 4);  // 16 KiB
    float* dist_ap = (float*)((char*)neg_bits + N_ROWS * 4);   // 24 KiB

    prep_kernel<<<N_ROWS, 256, 0, stream>>>(inputs, bfm, sq, neg_bits);
    gemm_kernel<<<NBLK2, 512, 131072, stream>>>(bfm, sq, neg_bits, dist_ap);
    finalize_kernel<<<1, 256, 0, stream>>>(neg_bits, dist_ap, out);
}